// Round 5
// baseline (275.873 us; speedup 1.0000x reference)
//
#include <hip/hip_runtime.h>
#include <math.h>

// Problem constants (match reference)
#define B_    8192
#define F_    64
#define V_    1000
#define E_    64
#define T_    2
#define NTOK_ 16
#define G_    4
#define D_    256
#define K_    128   // T*E
#define LN_EPS 1e-5f

#define XSP   136   // xs row stride in bf16 elements (fused fallback only)
#define HSP   260   // hs row stride in floats (256 + 4: float4-aligned rows)

typedef __attribute__((ext_vector_type(8))) short  frag_ab;  // 8 bf16 = 4 VGPRs
typedef __attribute__((ext_vector_type(4))) float  frag_cd;  // 4 fp32 acc
typedef __attribute__((ext_vector_type(4))) float  f32x4;    // native vec4 (NT-store legal)

static __device__ __forceinline__ unsigned short f2bf(float f) {
    // round-to-nearest-even fp32 -> bf16 (values are finite here)
    unsigned int u = __float_as_uint(f);
    u += 0x7FFFu + ((u >> 16) & 1u);
    return (unsigned short)(u >> 16);
}

// ---- prologue: W fp32 (D,K) -> bf16 in workspace (row-major, same layout) ----
__global__ __launch_bounds__(256) void convert_w_kernel(const float* __restrict__ W,
                                                        unsigned int* __restrict__ Wb_packed) {
    const int i = blockIdx.x * 256 + threadIdx.x;   // one uint = 2 bf16
    if (i < (D_ * K_) / 2) {
        const float2 v = *(const float2*)(W + (size_t)i * 2);
        const unsigned int p = (unsigned int)f2bf(v.x) | ((unsigned int)f2bf(v.y) << 16);
        __builtin_nontemporal_store(p, Wb_packed + i);
    }
}

// ================= Kernel A: gather + mean-pool -> x (B, NTOK, K) bf16 =======
// One block per batch row. Decoupled from the MLP so the compiler has free
// registers for memory-level parallelism: per iteration, 4 gather + 4 missing
// float4 loads are issued back-to-back (branchless mask blend), no MFMA/LN
// downstream constraining allocation. Normal (cached) stores for x: kernel B's
// identically-shaped grid maps block b to the same XCD, so its reads hit the
// L2 slice written here.
__global__ __launch_bounds__(256) void gather_pool_kernel(
    const int*   __restrict__ int_feats,     // (B, F)
    const int*   __restrict__ missing_mask,  // (B, F)
    const int*   __restrict__ group_idx,     // (NTOK, G)
    const float* __restrict__ emb_tables,    // (T, F, V, E)
    const float* __restrict__ missing_emb,   // (T, F, E)
    unsigned short* __restrict__ xout)       // (B, NTOK, K) bf16
{
    __shared__ int sid[F_];
    __shared__ int smask[F_];
    __shared__ int sg[NTOK_ * G_];

    const int tid = threadIdx.x;
    const int b   = blockIdx.x;

    if (tid < F_) {
        sid[tid]   = int_feats[b * F_ + tid];
        smask[tid] = missing_mask[b * F_ + tid];
        sg[tid]    = group_idx[tid];   // NTOK*G == F == 64
    }
    __syncthreads();

    // chunk c in [0,512): n = c>>5 (token), r4 = c&31, t = r4>>4, e = (r4&15)*4
    // 16 consecutive lanes cover one 256B embedding row -> coalesced dwordx4.
#pragma unroll
    for (int i = 0; i < 2; ++i) {
        const int c  = i * 256 + tid;
        const int n  = c >> 5;
        const int r4 = c & 31;
        const int t  = r4 >> 4;
        const int e  = (r4 & 15) * 4;

        // batch all 8 loads of this chunk (static indexing -> registers)
        float4 ev[G_], mv[G_];
        float  mk[G_];
#pragma unroll
        for (int g = 0; g < G_; ++g) {
            const int f  = sg[n * G_ + g];
            const int id = sid[f];
            ev[g] = *(const float4*)(emb_tables + (((size_t)(t * F_ + f) * V_) + id) * E_ + e);
            mv[g] = *(const float4*)(missing_emb + (size_t)(t * F_ + f) * E_ + e);
            mk[g] = (float)smask[f];
        }
        float ax = 0.f, ay = 0.f, az = 0.f, aw = 0.f;
#pragma unroll
        for (int g = 0; g < G_; ++g) {
            ax += ev[g].x + mk[g] * mv[g].x;
            ay += ev[g].y + mk[g] * mv[g].y;
            az += ev[g].z + mk[g] * mv[g].z;
            aw += ev[g].w + mk[g] * mv[g].w;
        }
        union { unsigned int u[2]; } pk;
        pk.u[0] = (unsigned int)f2bf(0.25f * ax) | ((unsigned int)f2bf(0.25f * ay) << 16);
        pk.u[1] = (unsigned int)f2bf(0.25f * az) | ((unsigned int)f2bf(0.25f * aw) << 16);
        *(uint2*)(xout + ((size_t)b * NTOK_ + n) * K_ + r4 * 4) = make_uint2(pk.u[0], pk.u[1]);
    }
}

// ================= Kernel B: MLP (x @ W^T + b -> silu -> LN) =================
// One block per batch row (16 tokens). x fragments read DIRECTLY from global:
// lane (m,q) reads token m's bytes {16q + 64s}, so each 64B line is fully
// consumed by 4 lanes — no LDS staging, no staging barrier. Then the proven
// swapped-operand MFMA + register LN + hs-transpose + NT stores.
__global__ __launch_bounds__(256) void mlp_kernel(
    const unsigned short* __restrict__ xin,  // (B, NTOK, K) bf16
    const unsigned short* __restrict__ Wb,   // (D, K) bf16
    const float* __restrict__ bias,          // (D,)
    const float* __restrict__ gamma,         // (D,)
    const float* __restrict__ beta,          // (D,)
    float*       __restrict__ out)           // (B, NTOK, D)
{
    __shared__ float hs[NTOK_][HSP];  // 16.6 KB
    __shared__ float ps [NTOK_][4];   // per-wave partial sum   (token, wave)
    __shared__ float pss[NTOK_][4];   // per-wave partial sumsq

    const int tid  = threadIdx.x;
    const int b    = blockIdx.x;
    const int lane = tid & 63;
    const int wave = tid >> 6;

    const int m = lane & 15;   // token index (D col of MFMA result)
    const int q = lane >> 4;   // quadrant

    // x fragment straight from global: lane holds x[token=m][k = 8q + j + 32s]
    const unsigned short* xrow = xin + ((size_t)b * NTOK_ + m) * K_ + 8 * q;
    frag_ab a[4];
#pragma unroll
    for (int s = 0; s < 4; ++s)
        a[s] = *(const frag_ab*)(xrow + 32 * s);

    float h[4][4];             // h[tt][reg]: silu outputs, cols 16*(4*wave+tt)+4q+reg, token m
    float s_acc = 0.f, ss_acc = 0.f;

#pragma unroll
    for (int tt = 0; tt < 4; ++tt) {
        const int nt   = wave * 4 + tt;        // n-tile
        const int nrow = nt * 16 + m;          // W row this lane supplies (A operand M dim)
        const unsigned short* wp = Wb + (size_t)nrow * K_ + 8 * q;

        frag_cd acc = {0.f, 0.f, 0.f, 0.f};
#pragma unroll
        for (int s = 0; s < 4; ++s) {
            const frag_ab wfr = *(const frag_ab*)(wp + 32 * s);
            // A = W (M = output col), B = x (N = token)
            acc = __builtin_amdgcn_mfma_f32_16x16x32_bf16(wfr, a[s], acc, 0, 0, 0);
        }
        const float4 bn = *(const float4*)(bias + nt * 16 + q * 4);
        const float bnv[4] = {bn.x, bn.y, bn.z, bn.w};
#pragma unroll
        for (int reg = 0; reg < 4; ++reg) {
            const float z  = acc[reg] + bnv[reg];
            const float hh = z / (1.f + __expf(-z));       // silu
            h[tt][reg] = hh;
            s_acc  += hh;
            ss_acc += hh * hh;
        }
    }

    // reduce across the 4 lanes holding token m (lanes m, m+16, m+32, m+48)
    s_acc  += __shfl_xor(s_acc,  16, 64);
    ss_acc += __shfl_xor(ss_acc, 16, 64);
    s_acc  += __shfl_xor(s_acc,  32, 64);
    ss_acc += __shfl_xor(ss_acc, 32, 64);
    if (q == 0) { ps[m][wave] = s_acc; pss[m][wave] = ss_acc; }
    __syncthreads();

    const float4 p4  = *(const float4*)(&ps[m][0]);
    const float4 pq4 = *(const float4*)(&pss[m][0]);
    const float s_tot  = (p4.x  + p4.y)  + (p4.z  + p4.w);
    const float ss_tot = (pq4.x + pq4.y) + (pq4.z + pq4.w);
    const float mu   = s_tot * (1.f / D_);
    const float var  = ss_tot * (1.f / D_) - mu * mu;
    const float rsig = rsqrtf(var + LN_EPS);

    // normalize in registers, transpose through LDS
#pragma unroll
    for (int tt = 0; tt < 4; ++tt) {
        const int col = (wave * 4 + tt) * 16 + q * 4;
        const float4 gm = *(const float4*)(gamma + col);
        const float4 bt = *(const float4*)(beta  + col);
        float4 o;
        o.x = (h[tt][0] - mu) * rsig * gm.x + bt.x;
        o.y = (h[tt][1] - mu) * rsig * gm.y + bt.y;
        o.z = (h[tt][2] - mu) * rsig * gm.z + bt.z;
        o.w = (h[tt][3] - mu) * rsig * gm.w + bt.w;
        *(float4*)(&hs[m][col]) = o;
    }
    __syncthreads();

    // coalesced copy-out, non-temporal; wave w stores tokens 4w..4w+3
#pragma unroll
    for (int qq = 0; qq < 4; ++qq) {
        const int n = wave * 4 + qq;
        const f32x4 v = *(const f32x4*)(&hs[n][lane * 4]);
        __builtin_nontemporal_store(v, (f32x4*)(out + ((size_t)b * NTOK_ + n) * D_ + lane * 4));
    }
}

// ================= Fallback: fused kernel (round-4 proven) ===================
__global__ __launch_bounds__(256) void fused_tokenizer_kernel(
    const int*   __restrict__ int_feats,
    const int*   __restrict__ missing_mask,
    const int*   __restrict__ group_idx,
    const float* __restrict__ emb_tables,
    const float* __restrict__ missing_emb,
    const unsigned short* __restrict__ Wb,
    const float* __restrict__ bias,
    const float* __restrict__ gamma,
    const float* __restrict__ beta,
    float*       __restrict__ out)
{
    __shared__ __align__(16) char smem[NTOK_ * HSP * 4];
    unsigned short (*xs)[XSP] = (unsigned short (*)[XSP])smem;
    float          (*hs)[HSP] = (float (*)[HSP])smem;

    __shared__ int   sid[F_];
    __shared__ int   smask[F_];
    __shared__ int   sg[NTOK_ * G_];
    __shared__ float ps [NTOK_][4];
    __shared__ float pss[NTOK_][4];

    const int tid  = threadIdx.x;
    const int b    = blockIdx.x;
    const int lane = tid & 63;
    const int wave = tid >> 6;

    if (tid < F_) {
        sid[tid]   = int_feats[b * F_ + tid];
        smask[tid] = missing_mask[b * F_ + tid];
        sg[tid]    = group_idx[tid];
    }
    __syncthreads();

#pragma unroll
    for (int i = 0; i < 2; ++i) {
        const int c  = i * 256 + tid;
        const int n  = c >> 5;
        const int r4 = c & 31;
        const int t  = r4 >> 4;
        const int e  = (r4 & 15) * 4;
        float ax = 0.f, ay = 0.f, az = 0.f, aw = 0.f;
#pragma unroll
        for (int g = 0; g < G_; ++g) {
            const int f  = sg[n * G_ + g];
            const int id = sid[f];
            const float4 v = *(const float4*)(emb_tables + (((size_t)(t * F_ + f) * V_) + id) * E_ + e);
            float vx = v.x, vy = v.y, vz = v.z, vw = v.w;
            if (smask[f]) {
                const float4 mv = *(const float4*)(missing_emb + (size_t)(t * F_ + f) * E_ + e);
                vx += mv.x; vy += mv.y; vz += mv.z; vw += mv.w;
            }
            ax += vx; ay += vy; az += vz; aw += vw;
        }
        union { unsigned int u[2]; } pk;
        pk.u[0] = (unsigned int)f2bf(0.25f * ax) | ((unsigned int)f2bf(0.25f * ay) << 16);
        pk.u[1] = (unsigned int)f2bf(0.25f * az) | ((unsigned int)f2bf(0.25f * aw) << 16);
        *(uint2*)(&xs[n][r4 * 4]) = make_uint2(pk.u[0], pk.u[1]);
    }
    __syncthreads();

    const int m = lane & 15;
    const int q = lane >> 4;

    frag_ab a[4];
#pragma unroll
    for (int s = 0; s < 4; ++s)
        a[s] = *(const frag_ab*)(&xs[m][32 * s + 8 * q]);

    float h[4][4];
    float s_acc = 0.f, ss_acc = 0.f;

#pragma unroll
    for (int tt = 0; tt < 4; ++tt) {
        const int nt   = wave * 4 + tt;
        const int nrow = nt * 16 + m;
        const unsigned short* wp = Wb + (size_t)nrow * K_ + 8 * q;

        frag_cd acc = {0.f, 0.f, 0.f, 0.f};
#pragma unroll
        for (int s = 0; s < 4; ++s) {
            const frag_ab wfr = *(const frag_ab*)(wp + 32 * s);
            acc = __builtin_amdgcn_mfma_f32_16x16x32_bf16(wfr, a[s], acc, 0, 0, 0);
        }
        const float4 bn = *(const float4*)(bias + nt * 16 + q * 4);
        const float bnv[4] = {bn.x, bn.y, bn.z, bn.w};
#pragma unroll
        for (int reg = 0; reg < 4; ++reg) {
            const float z  = acc[reg] + bnv[reg];
            const float hh = z / (1.f + __expf(-z));
            h[tt][reg] = hh;
            s_acc  += hh;
            ss_acc += hh * hh;
        }
    }

    s_acc  += __shfl_xor(s_acc,  16, 64);
    ss_acc += __shfl_xor(ss_acc, 16, 64);
    s_acc  += __shfl_xor(s_acc,  32, 64);
    ss_acc += __shfl_xor(ss_acc, 32, 64);
    if (q == 0) { ps[m][wave] = s_acc; pss[m][wave] = ss_acc; }
    __syncthreads();

    const float4 p4  = *(const float4*)(&ps[m][0]);
    const float4 pq4 = *(const float4*)(&pss[m][0]);
    const float s_tot  = (p4.x  + p4.y)  + (p4.z  + p4.w);
    const float ss_tot = (pq4.x + pq4.y) + (pq4.z + pq4.w);
    const float mu   = s_tot * (1.f / D_);
    const float var  = ss_tot * (1.f / D_) - mu * mu;
    const float rsig = rsqrtf(var + LN_EPS);

#pragma unroll
    for (int tt = 0; tt < 4; ++tt) {
        const int col = (wave * 4 + tt) * 16 + q * 4;
        const float4 gm = *(const float4*)(gamma + col);
        const float4 bt = *(const float4*)(beta  + col);
        float4 o;
        o.x = (h[tt][0] - mu) * rsig * gm.x + bt.x;
        o.y = (h[tt][1] - mu) * rsig * gm.y + bt.y;
        o.z = (h[tt][2] - mu) * rsig * gm.z + bt.z;
        o.w = (h[tt][3] - mu) * rsig * gm.w + bt.w;
        *(float4*)(&hs[m][col]) = o;
    }
    __syncthreads();

#pragma unroll
    for (int qq = 0; qq < 4; ++qq) {
        const int n = wave * 4 + qq;
        const f32x4 v = *(const f32x4*)(&hs[n][lane * 4]);
        __builtin_nontemporal_store(v, (f32x4*)(out + ((size_t)b * NTOK_ + n) * D_ + lane * 4));
    }
}

extern "C" void kernel_launch(void* const* d_in, const int* in_sizes, int n_in,
                              void* d_out, int out_size, void* d_ws, size_t ws_size,
                              hipStream_t stream) {
    const int*   int_feats    = (const int*)  d_in[0];
    const int*   missing_mask = (const int*)  d_in[1];
    const int*   group_idx    = (const int*)  d_in[2];
    const float* emb_tables   = (const float*)d_in[3];
    const float* missing_emb  = (const float*)d_in[4];
    const float* W            = (const float*)d_in[5];
    const float* bias         = (const float*)d_in[6];
    const float* gamma        = (const float*)d_in[7];
    const float* beta         = (const float*)d_in[8];
    float* out = (float*)d_out;

    unsigned short* Wb = (unsigned short*)d_ws;                       // 64 KB
    const size_t wb_bytes = (size_t)D_ * K_ * 2;                      // 65536
    const size_t x_bytes  = (size_t)B_ * NTOK_ * K_ * 2;              // 32 MB
    unsigned short* x = (unsigned short*)((char*)d_ws + wb_bytes);

    convert_w_kernel<<<(D_ * K_ / 2 + 255) / 256, 256, 0, stream>>>(W, (unsigned int*)Wb);

    if (ws_size >= wb_bytes + x_bytes) {
        gather_pool_kernel<<<B_, 256, 0, stream>>>(
            int_feats, missing_mask, group_idx, emb_tables, missing_emb, x);
        mlp_kernel<<<B_, 256, 0, stream>>>(x, Wb, bias, gamma, beta, out);
    } else {
        fused_tokenizer_kernel<<<B_, 256, 0, stream>>>(
            int_feats, missing_mask, group_idx, emb_tables, missing_emb,
            Wb, bias, gamma, beta, out);
    }
}

// Round 6
// 222.927 us; speedup vs baseline: 1.2375x; 1.2375x over previous
//
#include <hip/hip_runtime.h>
#include <math.h>

// Problem constants (match reference)
#define B_    8192
#define F_    64
#define V_    1000
#define E_    64
#define T_    2
#define NTOK_ 16
#define G_    4
#define D_    256
#define K_    128   // T*E
#define LN_EPS 1e-5f

#define RPB   2              // batch rows per block
#define TOK2  (NTOK_ * RPB)  // 32 tokens per block
#define XSP   136            // xs row stride in bf16 elements (128 + 8 pad)
#define HSP   260            // hs row stride in floats (256 + 4)

typedef __attribute__((ext_vector_type(8))) short  frag_ab;  // 8 bf16 = 4 VGPRs
typedef __attribute__((ext_vector_type(4))) float  frag_cd;  // 4 fp32 acc
typedef __attribute__((ext_vector_type(4))) float  f32x4;    // native vec4 (NT-store legal)

static __device__ __forceinline__ unsigned short f2bf(float f) {
    // round-to-nearest-even fp32 -> bf16 (values are finite here)
    unsigned int u = __float_as_uint(f);
    u += 0x7FFFu + ((u >> 16) & 1u);
    return (unsigned short)(u >> 16);
}

// ---- prologue: W fp32 (D,K) -> bf16 in workspace (row-major, same layout) ----
__global__ __launch_bounds__(256) void convert_w_kernel(const float* __restrict__ W,
                                                        unsigned int* __restrict__ Wb_packed) {
    const int i = blockIdx.x * 256 + threadIdx.x;   // one uint = 2 bf16
    if (i < (D_ * K_) / 2) {
        const float2 v = *(const float2*)(W + (size_t)i * 2);
        const unsigned int p = (unsigned int)f2bf(v.x) | ((unsigned int)f2bf(v.y) << 16);
        __builtin_nontemporal_store(p, Wb_packed + i);
    }
}

// One block per TWO batch rows (grid 4096). 256 threads = 4 waves.
// r5 decomposition showed the MLP phase (not the gather) dominates, stalled on
// L2-latency W-fragment loads (VGPR=32 => ~no loads in flight). This version:
//  - 2 rows/block: each W fragment feeds 2 MFMA streams (acc0/acc1) -> W-load
//    count per unit work halves, 8 MFMAs of shadow per load round.
//  - explicit W double-buffer (compile-time indexed after unroll): tt+1's
//    loads issue before tt's MFMAs.
//  - deferred LN: raw silu -> hs during the loop (frees h regs); normalize at
//    phase-3 readout using ps/pss.
//  - launch_bounds(256,4): VGPR cap 128. LDS ~35.6KB -> 4 blocks/CU.
__global__ __launch_bounds__(256, 4) void fused_tokenizer_kernel(
    const int*   __restrict__ int_feats,     // (B, F)
    const int*   __restrict__ missing_mask,  // (B, F)
    const int*   __restrict__ group_idx,     // (NTOK, G)
    const float* __restrict__ emb_tables,    // (T, F, V, E)
    const float* __restrict__ missing_emb,   // (T, F, E)
    const unsigned short* __restrict__ Wb,   // (D, K) bf16
    const float* __restrict__ bias,          // (D,)
    const float* __restrict__ gamma,         // (D,)
    const float* __restrict__ beta,          // (D,)
    float*       __restrict__ out)           // (B, NTOK, D)
{
    // hs (32x260 fp32 = 33.3 KB) aliases xs (32x136 bf16 = 8.7 KB).
    __shared__ __align__(16) char smem[TOK2 * HSP * 4];
    unsigned short (*xs)[XSP] = (unsigned short (*)[XSP])smem;
    float          (*hs)[HSP] = (float (*)[HSP])smem;

    __shared__ int   sid[RPB][F_];
    __shared__ int   smask[RPB][F_];
    __shared__ int   sg[NTOK_ * G_];
    __shared__ float ps [TOK2][4];   // per-wave partial sum   (token, wave)
    __shared__ float pss[TOK2][4];   // per-wave partial sumsq

    const int tid  = threadIdx.x;
    const int b0   = blockIdx.x * RPB;
    const int lane = tid & 63;
    const int wave = tid >> 6;

    if (tid < RPB * F_) {
        const int r = tid >> 6, f = tid & 63;
        sid[r][f]   = int_feats[(b0 + r) * F_ + f];
        smask[r][f] = missing_mask[(b0 + r) * F_ + f];
    }
    if (tid < F_) sg[tid] = group_idx[tid];   // NTOK*G == F == 64
    __syncthreads();

    // ---- Phase 1: gather + mean-pool, 2 rows (1024 float4-chunks) ----
    // chunk c: row = c>>9, cc = c&511, n = cc>>5 (token), r4 = cc&31,
    // t = r4>>4, e = (r4&15)*4. 16 consecutive lanes cover one 256B embedding
    // row -> coalesced dwordx4. Loads batched (branchless) for MLP depth.
#pragma unroll
    for (int i = 0; i < 4; ++i) {
        const int c   = i * 256 + tid;
        const int row = c >> 9;
        const int cc  = c & 511;
        const int n   = cc >> 5;
        const int r4  = cc & 31;
        const int t   = r4 >> 4;
        const int e   = (r4 & 15) * 4;

        float4 ev[G_], mv[G_];
        float  mk[G_];
#pragma unroll
        for (int g = 0; g < G_; ++g) {
            const int f  = sg[n * G_ + g];
            const int id = sid[row][f];
            ev[g] = *(const float4*)(emb_tables + (((size_t)(t * F_ + f) * V_) + id) * E_ + e);
            mv[g] = *(const float4*)(missing_emb + (size_t)(t * F_ + f) * E_ + e);
            mk[g] = (float)smask[row][f];
        }
        float ax = 0.f, ay = 0.f, az = 0.f, aw = 0.f;
#pragma unroll
        for (int g = 0; g < G_; ++g) {
            ax += ev[g].x + mk[g] * mv[g].x;
            ay += ev[g].y + mk[g] * mv[g].y;
            az += ev[g].z + mk[g] * mv[g].z;
            aw += ev[g].w + mk[g] * mv[g].w;
        }
        union { unsigned int u[2]; } pk;
        pk.u[0] = (unsigned int)f2bf(0.25f * ax) | ((unsigned int)f2bf(0.25f * ay) << 16);
        pk.u[1] = (unsigned int)f2bf(0.25f * az) | ((unsigned int)f2bf(0.25f * aw) << 16);
        *(uint2*)(&xs[row * NTOK_ + n][r4 * 4]) = make_uint2(pk.u[0], pk.u[1]);
    }
    __syncthreads();

    // ---- Phase 2: swapped-operand MFMA, 2 rows sharing W fragments ----
    const int m = lane & 15;   // token index within a row (D col of MFMA result)
    const int q = lane >> 4;   // quadrant

    frag_ab a0[4], a1[4];
#pragma unroll
    for (int s = 0; s < 4; ++s) {
        a0[s] = *(const frag_ab*)(&xs[m][32 * s + 8 * q]);
        a1[s] = *(const frag_ab*)(&xs[NTOK_ + m][32 * s + 8 * q]);
    }
    __syncthreads();   // all waves' xs reads done before hs writes (aliased)

    float s0 = 0.f, ss0 = 0.f, s1 = 0.f, ss1 = 0.f;

    frag_ab wb_[2][4];
    {
        const unsigned short* wp = Wb + (size_t)((wave * 4 + 0) * 16 + m) * K_ + 8 * q;
#pragma unroll
        for (int s = 0; s < 4; ++s) wb_[0][s] = *(const frag_ab*)(wp + 32 * s);
    }

#pragma unroll
    for (int tt = 0; tt < 4; ++tt) {
        const int cur = tt & 1;           // compile-time after unroll
        if (tt < 3) {
            const unsigned short* wp = Wb + (size_t)((wave * 4 + tt + 1) * 16 + m) * K_ + 8 * q;
#pragma unroll
            for (int s = 0; s < 4; ++s) wb_[cur ^ 1][s] = *(const frag_ab*)(wp + 32 * s);
        }
        frag_cd acc0 = {0.f, 0.f, 0.f, 0.f};
        frag_cd acc1 = {0.f, 0.f, 0.f, 0.f};
#pragma unroll
        for (int s = 0; s < 4; ++s) {
            acc0 = __builtin_amdgcn_mfma_f32_16x16x32_bf16(wb_[cur][s], a0[s], acc0, 0, 0, 0);
            acc1 = __builtin_amdgcn_mfma_f32_16x16x32_bf16(wb_[cur][s], a1[s], acc1, 0, 0, 0);
        }
        const int nt  = wave * 4 + tt;
        const int col = nt * 16 + q * 4;
        const float4 bn = *(const float4*)(bias + col);
        const float bnv[4] = {bn.x, bn.y, bn.z, bn.w};
        float4 h0, h1;
#pragma unroll
        for (int reg = 0; reg < 4; ++reg) {
            const float z0 = acc0[reg] + bnv[reg];
            const float z1 = acc1[reg] + bnv[reg];
            const float v0 = z0 / (1.f + __expf(-z0));   // silu
            const float v1 = z1 / (1.f + __expf(-z1));
            s0 += v0; ss0 += v0 * v0;
            s1 += v1; ss1 += v1 * v1;
            ((float*)&h0)[reg] = v0;
            ((float*)&h1)[reg] = v1;
        }
        *(float4*)(&hs[m][col])         = h0;   // raw silu; LN applied at readout
        *(float4*)(&hs[NTOK_ + m][col]) = h1;
    }

    // reduce across the 4 lanes holding token m (lanes m, m+16, m+32, m+48)
    s0  += __shfl_xor(s0,  16, 64);  ss0 += __shfl_xor(ss0, 16, 64);
    s0  += __shfl_xor(s0,  32, 64);  ss0 += __shfl_xor(ss0, 32, 64);
    s1  += __shfl_xor(s1,  16, 64);  ss1 += __shfl_xor(ss1, 16, 64);
    s1  += __shfl_xor(s1,  32, 64);  ss1 += __shfl_xor(ss1, 32, 64);
    if (q == 0) {
        ps [m][wave] = s0;  pss[m][wave] = ss0;
        ps [NTOK_ + m][wave] = s1;  pss[NTOK_ + m][wave] = ss1;
    }
    __syncthreads();

    // ---- Phase 3: LN at readout + coalesced NT stores; wave w: tokens 8w..8w+7 ----
    const float4 gm = *(const float4*)(gamma + lane * 4);
    const float4 bt = *(const float4*)(beta  + lane * 4);
#pragma unroll
    for (int qq = 0; qq < 8; ++qq) {
        const int n = wave * 8 + qq;            // 0..31
        const float4 p4  = *(const float4*)(&ps[n][0]);
        const float4 pq4 = *(const float4*)(&pss[n][0]);
        const float s_tot  = (p4.x  + p4.y)  + (p4.z  + p4.w);
        const float ss_tot = (pq4.x + pq4.y) + (pq4.z + pq4.w);
        const float mu   = s_tot * (1.f / D_);
        const float var  = ss_tot * (1.f / D_) - mu * mu;
        const float rsig = rsqrtf(var + LN_EPS);

        const float4 v = *(const float4*)(&hs[n][lane * 4]);
        f32x4 o;
        o.x = (v.x - mu) * rsig * gm.x + bt.x;
        o.y = (v.y - mu) * rsig * gm.y + bt.y;
        o.z = (v.z - mu) * rsig * gm.z + bt.z;
        o.w = (v.w - mu) * rsig * gm.w + bt.w;
        const size_t orow = ((size_t)(b0 + (n >> 4)) * NTOK_ + (n & 15)) * D_;
        __builtin_nontemporal_store(o, (f32x4*)(out + orow + lane * 4));
    }
}

extern "C" void kernel_launch(void* const* d_in, const int* in_sizes, int n_in,
                              void* d_out, int out_size, void* d_ws, size_t ws_size,
                              hipStream_t stream) {
    const int*   int_feats    = (const int*)  d_in[0];
    const int*   missing_mask = (const int*)  d_in[1];
    const int*   group_idx    = (const int*)  d_in[2];
    const float* emb_tables   = (const float*)d_in[3];
    const float* missing_emb  = (const float*)d_in[4];
    const float* W            = (const float*)d_in[5];
    const float* bias         = (const float*)d_in[6];
    const float* gamma        = (const float*)d_in[7];
    const float* beta         = (const float*)d_in[8];
    float* out = (float*)d_out;

    unsigned short* Wb = (unsigned short*)d_ws;   // 64 KB bf16 copy of W

    convert_w_kernel<<<(D_ * K_ / 2 + 255) / 256, 256, 0, stream>>>(W, (unsigned int*)Wb);
    fused_tokenizer_kernel<<<B_ / RPB, 256, 0, stream>>>(
        int_feats, missing_mask, group_idx, emb_tables, missing_emb,
        Wb, bias, gamma, beta, out);
}